// Round 15
// baseline (186.954 us; speedup 1.0000x reference)
//
#include <hip/hip_runtime.h>
#include <hip/hip_bf16.h>
#include <stdint.h>

typedef __attribute__((ext_vector_type(4))) float floatx4;
typedef __attribute__((ext_vector_type(16))) float floatx16;
typedef __attribute__((ext_vector_type(4))) int intx4;
typedef __attribute__((ext_vector_type(8))) int intx8;
typedef __attribute__((ext_vector_type(2))) unsigned int uint2v;
typedef unsigned long long u64;

static constexpr int NROWS = 32768;
static constexpr int NCODE = 8192;
static constexpr int QELEMS = 8388608;
static constexpr float CSCALE = 8192.0f;

// ---- fused prep: [0,1024) z->fp8 transpose, [1024,3072) codebook, [3072,3088) amin ----
__global__ __launch_bounds__(256) void prep_all(
    const float* __restrict__ z, const float* __restrict__ cb,
    unsigned char* __restrict__ z8, unsigned char* __restrict__ c8,
    float* __restrict__ norms, u64* __restrict__ amin)
{
  const int bid = blockIdx.x;
  const int t = threadIdx.x;
  if (bid < 1024) {
    __shared__ float tile[32][260];
    const int b = bid & 31, db = (bid >> 5) & 7, hwb = bid >> 8;
    const int d0 = db * 32, hw0 = hwb * 256;
    const float* src = z + (((size_t)b * 256 + d0) << 10) + hw0;
#pragma unroll
    for (int i = 0; i < 8; ++i) {
      int idx = i * 256 + t;
      int r = idx >> 6, c4 = (idx & 63) * 4;
      *(floatx4*)&tile[r][c4] = *(const floatx4*)&src[((size_t)r << 10) + c4];
    }
    __syncthreads();
    const int dq = t & 3;
    const int hb = t >> 2;
#pragma unroll
    for (int it = 0; it < 4; ++it) {
      int h = hb + it * 64;
      float f[8];
#pragma unroll
      for (int i = 0; i < 8; ++i) f[i] = tile[dq * 8 + i][h];
      int lo = __builtin_amdgcn_cvt_pk_fp8_f32(f[0], f[1], 0, false);
      lo = __builtin_amdgcn_cvt_pk_fp8_f32(f[2], f[3], lo, true);
      int hi = __builtin_amdgcn_cvt_pk_fp8_f32(f[4], f[5], 0, false);
      hi = __builtin_amdgcn_cvt_pk_fp8_f32(f[6], f[7], hi, true);
      uint2v o; o[0] = (unsigned)lo; o[1] = (unsigned)hi;
      *(uint2v*)&z8[((size_t)(b * 1024 + hw0 + h)) * 256 + d0 + dq * 8] = o;
    }
  } else if (bid < 3072) {
    const int k = (bid - 1024) * 4 + (t >> 6);
    const int lane = t & 63;
    floatx4 v = *(const floatx4*)&cb[((size_t)k << 8) + lane * 4];
    float a = v[0] * CSCALE, b2 = v[1] * CSCALE, c = v[2] * CSCALE, d2 = v[3] * CSCALE;
    int r = __builtin_amdgcn_cvt_pk_fp8_f32(a, b2, 0, false);
    r = __builtin_amdgcn_cvt_pk_fp8_f32(c, d2, r, true);
    *(unsigned int*)&c8[((size_t)k << 8) + lane * 4] = (unsigned)r;
    float s = a * a + b2 * b2 + c * c + d2 * d2;  // ||8192 c||^2
#pragma unroll
    for (int off = 32; off; off >>= 1) s += __shfl_down(s, off);
    if (lane == 0) norms[k] = s;
  } else {
    const int base = (bid - 3072) * 2048;
#pragma unroll
    for (int i = 0; i < 8; ++i) amin[base + i * 256 + t] = ~0ull;
  }
}

// ---- main: MX-fp8 32x32x64, A whole-K in VGPR, B panel in PADDED LDS rows ----
// Rows padded to 272 B -> bank-group = (row+slot)&7 rotates: zero-conflict
// reads AND pure immediate-offset addressing (no XOR VALU in K-loop).
// Barrier-free K-loop: 32 ds_read_b128 + 32 MFMA, compiler-scheduled.
__global__ __launch_bounds__(256, 2) void gemm_argmin(
    const unsigned char* __restrict__ z8, const unsigned char* __restrict__ c8,
    const float* __restrict__ norms, u64* __restrict__ amin)
{
  // B panel: 256 rows x 272 B = 69632; best2 u64[512] at +69632
  __shared__ alignas(16) unsigned char lds8[69632 + 4096];

  const int tid = threadIdx.x;
  const int lane = tid & 63;
  const int wid = tid >> 6;
  const int wm = wid >> 1;  // code half (64 codes)
  const int wn = wid & 1;   // zrow half (128 zrows)

  // XCD chunked swizzle: nwg = 8192 (%8 == 0)
  const int bid = blockIdx.x;
  const int swz = (bid & 7) * 1024 + (bid >> 3);
  const int cx = swz & 63;   // 64 code panels
  const int cy = swz >> 6;   // 128 zrow panels
  const int m0 = cx * 128;
  const int n0 = cy * 256;

  const int l31 = lane & 31;
  const int hi = lane >> 5;
  const int k2 = hi << 1;    // logical 16B-slot base within a kt's 64B chunk

  // ---- A (codes): global -> VGPR, whole K=256; one base + immediate offsets ----
  intx8 af[2][4];  // [ti][kt]
#pragma unroll
  for (int ti = 0; ti < 2; ++ti) {
    const unsigned char* arow =
        c8 + ((size_t)(m0 + wm * 64 + ti * 32 + l31) << 8) + k2 * 16;
#pragma unroll
    for (int kt = 0; kt < 4; ++kt) {
      intx4 lo = *(const intx4*)(arow + kt * 64);
      intx4 hv = *(const intx4*)(arow + kt * 64 + 16);
      intx8 o;
#pragma unroll
      for (int w = 0; w < 4; ++w) { o[w] = lo[w]; o[4 + w] = hv[w]; }
      af[ti][kt] = o;
    }
  }

  // ---- B: reg-stage 64 KB panel into padded rows (two 8-deep batches) ----
  // global: base + c*4096 (coalesced 4 KB/instr); LDS dest: row=(c*256+tid)>>4,
  // slot=tid&15 -> byte = row*272 + slot*16 = dstb + c*4352. Writes: 8 lanes
  // per 4-bank group per instr = conflict-free.
  {
    const unsigned char* gsrc = z8 + ((size_t)n0 << 8) + tid * 16;
    unsigned char* dstb = lds8 + (tid >> 4) * 272 + (tid & 15) * 16;
    intx4 tmp[8];
#pragma unroll
    for (int c = 0; c < 8; ++c) tmp[c] = *(const intx4*)(gsrc + c * 4096);
#pragma unroll
    for (int c = 0; c < 8; ++c) *(intx4*)(dstb + c * 4352) = tmp[c];
#pragma unroll
    for (int c = 0; c < 8; ++c) tmp[c] = *(const intx4*)(gsrc + (8 + c) * 4096);
#pragma unroll
    for (int c = 0; c < 8; ++c) *(intx4*)(dstb + (8 + c) * 4352) = tmp[c];
  }
  __syncthreads();

  floatx16 acc[2][4];
#pragma unroll
  for (int i = 0; i < 2; ++i)
#pragma unroll
    for (int j = 0; j < 4; ++j)
#pragma unroll
      for (int e = 0; e < 16; ++e) acc[i][j][e] = 0.f;

  // ---- barrier-free K-loop: one per-lane base, all-immediate ds_reads ----
  {
    const unsigned char* rb = lds8 + (size_t)(wn * 128 + l31) * 272 + k2 * 16;
#pragma unroll
    for (int kt = 0; kt < 4; ++kt) {
      intx8 bf[4];
#pragma unroll
      for (int tj = 0; tj < 4; ++tj) {
        intx4 lo = *(const intx4*)(rb + tj * 8704 + kt * 64);
        intx4 hv = *(const intx4*)(rb + tj * 8704 + kt * 64 + 16);
        intx8 o;
#pragma unroll
        for (int w = 0; w < 4; ++w) { o[w] = lo[w]; o[4 + w] = hv[w]; }
        bf[tj] = o;
      }
#pragma unroll
      for (int ti = 0; ti < 2; ++ti)
#pragma unroll
        for (int tj = 0; tj < 4; ++tj)
          acc[ti][tj] = __builtin_amdgcn_mfma_scale_f32_32x32x64_f8f6f4(
              af[ti][kt], bf[tj], acc[ti][tj], 0, 0, 0, 127, 0, 127);
    }
  }

  // ---- epilogue: norms (loaded now; hides under other block's MFMA) ----
  floatx4 nv[2][4];
#pragma unroll
  for (int ti = 0; ti < 2; ++ti)
#pragma unroll
    for (int rq = 0; rq < 4; ++rq)
      nv[ti][rq] = *(const floatx4*)&norms[m0 + wm * 64 + ti * 32 + rq * 8 + 4 * hi];

  // D layout: zrow = lane&31; code-in-tile = (reg&3) + 8*(reg>>2) + 4*hi
  u64* best2 = (u64*)(lds8 + 69632);  // [256 zrows][2 wm]
#pragma unroll
  for (int tj = 0; tj < 4; ++tj) {
    float best = __builtin_inff();
    int bc = 0;
    // ascending code order within lane: ti, rq, rl
#pragma unroll
    for (int ti = 0; ti < 2; ++ti)
#pragma unroll
      for (int rq = 0; rq < 4; ++rq)
#pragma unroll
        for (int rl = 0; rl < 4; ++rl) {
          float sc = fmaf(acc[ti][tj][rq * 4 + rl], -16384.f, nv[ti][rq][rl]);
          int cd = m0 + wm * 64 + ti * 32 + rq * 8 + 4 * hi + rl;
          if (sc < best) { best = sc; bc = cd; }
        }
    uint32_t u = __float_as_uint(best);
    u ^= ((uint32_t)((int32_t)u >> 31) | 0x80000000u);  // monotone-sortable
    u64 p = ((u64)u << 32) | (uint32_t)bc;
    {
      u64 o = (u64)__shfl_xor((long long)p, 32);
      p = o < p ? o : p;
    }
    if (lane < 32) best2[(size_t)(wn * 128 + tj * 32 + l31) * 2 + wm] = p;
  }
  __syncthreads();
  {
    u64 a = best2[tid * 2], b = best2[tid * 2 + 1];
    u64 p = a < b ? a : b;
    atomicMin(&amin[n0 + tid], p);
  }
}

// ---- gather + output + per-block loss partials (8 elems/thread, amin direct) ----
__global__ __launch_bounds__(256) void gather_out(
    const float* __restrict__ z, const float* __restrict__ cb,
    const u64* __restrict__ amin,
    float* __restrict__ out, float* __restrict__ partial)
{
  const int t = threadIdx.x;
  const size_t e0 = ((size_t)blockIdx.x * 256 + t) * 8;
  const int d = (int)((e0 >> 10) & 255);
  const int b = (int)(e0 >> 18);
  const int n0 = b * 1024 + (int)(e0 & 1023);
  uint32_t kv[8];
#pragma unroll
  for (int m = 0; m < 8; ++m) kv[m] = (uint32_t)amin[n0 + m];
  floatx4 z0 = *(const floatx4*)&z[e0];
  floatx4 z1 = *(const floatx4*)&z[e0 + 4];
  floatx4 q0, q1;
#pragma unroll
  for (int m = 0; m < 4; ++m) {
    q0[m] = cb[((size_t)kv[m] << 8) + d];
    q1[m] = cb[((size_t)kv[4 + m] << 8) + d];
  }
  *(floatx4*)&out[e0] = q0;
  *(floatx4*)&out[e0 + 4] = q1;
  float s = 0.f;
#pragma unroll
  for (int m = 0; m < 4; ++m) {
    float d0 = z0[m] - q0[m], d1 = z1[m] - q1[m];
    s += d0 * d0 + d1 * d1;
  }
#pragma unroll
  for (int off = 32; off; off >>= 1) s += __shfl_down(s, off);
  __shared__ float ps[4];
  if ((t & 63) == 0) ps[t >> 6] = s;
  __syncthreads();
  if (t == 0) partial[blockIdx.x] = ps[0] + ps[1] + ps[2] + ps[3];
}

// ---- deterministic final reduction + scalar outputs ----
__global__ __launch_bounds__(256) void finalize(const float* __restrict__ partial,
                                                float* __restrict__ out)
{
  const int t = threadIdx.x;
  float s = 0.f;
#pragma unroll
  for (int i = 0; i < 16; ++i) s += partial[i * 256 + t];
#pragma unroll
  for (int off = 32; off; off >>= 1) s += __shfl_down(s, off);
  __shared__ float ps[4];
  if ((t & 63) == 0) ps[t >> 6] = s;
  __syncthreads();
  if (t == 0) {
    float m = (ps[0] + ps[1] + ps[2] + ps[3]) / (float)QELEMS;
    out[QELEMS] = m;             // codebook_loss
    out[QELEMS + 1] = 0.2f * m;  // commitment_loss
  }
}

extern "C" void kernel_launch(void* const* d_in, const int* in_sizes, int n_in,
                              void* d_out, int out_size, void* d_ws, size_t ws_size,
                              hipStream_t stream)
{
  const float* z = (const float*)d_in[0];
  const float* cb = (const float*)d_in[1];
  float* out = (float*)d_out;
  char* ws = (char*)d_ws;

  // ws layout (bytes)
  unsigned char* z8 = (unsigned char*)(ws + 0);       //  8,388,608
  unsigned char* c8 = (unsigned char*)(ws + 8388608); //  2,097,152
  float* norms = (float*)(ws + 10485760);             //    131,072 (padded)
  u64* amin = (u64*)(ws + 10616832);                  //    262,144
  float* lpart = (float*)(ws + 10878976);             //     16,384
  // total: 10,895,360 bytes

  prep_all<<<3088, 256, 0, stream>>>(z, cb, z8, c8, norms, amin);
  gemm_argmin<<<8192, 256, 0, stream>>>(z8, c8, norms, amin);
  gather_out<<<QELEMS / 2048, 256, 0, stream>>>(z, cb, amin, out, lpart);
  finalize<<<1, 256, 0, stream>>>(lpart, out);
}

// Round 16
// 156.203 us; speedup vs baseline: 1.1969x; 1.1969x over previous
//
#include <hip/hip_runtime.h>
#include <hip/hip_bf16.h>
#include <stdint.h>

typedef __attribute__((ext_vector_type(4))) float floatx4;
typedef __attribute__((ext_vector_type(16))) float floatx16;
typedef __attribute__((ext_vector_type(4))) int intx4;
typedef __attribute__((ext_vector_type(8))) int intx8;
typedef __attribute__((ext_vector_type(4))) unsigned int uint4v;
typedef __attribute__((ext_vector_type(2))) unsigned int uint2v;
typedef unsigned long long u64;

static constexpr int NROWS = 32768;
static constexpr int NCODE = 8192;
static constexpr int QELEMS = 8388608;
static constexpr float CSCALE = 8192.0f;

// ---- fused prep: [0,1024) z->fp8 transpose, [1024,3072) codebook+norms ----
__global__ __launch_bounds__(256) void prep_all(
    const float* __restrict__ z, const float* __restrict__ cb,
    unsigned char* __restrict__ z8, unsigned char* __restrict__ c8,
    float* __restrict__ norms)
{
  const int bid = blockIdx.x;
  const int t = threadIdx.x;
  if (bid < 1024) {
    __shared__ float tile[32][260];
    const int b = bid & 31, db = (bid >> 5) & 7, hwb = bid >> 8;
    const int d0 = db * 32, hw0 = hwb * 256;
    const float* src = z + (((size_t)b * 256 + d0) << 10) + hw0;
#pragma unroll
    for (int i = 0; i < 8; ++i) {
      int idx = i * 256 + t;
      int r = idx >> 6, c4 = (idx & 63) * 4;
      *(floatx4*)&tile[r][c4] = *(const floatx4*)&src[((size_t)r << 10) + c4];
    }
    __syncthreads();
    const int dq = t & 3;
    const int hb = t >> 2;
#pragma unroll
    for (int it = 0; it < 4; ++it) {
      int h = hb + it * 64;
      float f[8];
#pragma unroll
      for (int i = 0; i < 8; ++i) f[i] = tile[dq * 8 + i][h];
      int lo = __builtin_amdgcn_cvt_pk_fp8_f32(f[0], f[1], 0, false);
      lo = __builtin_amdgcn_cvt_pk_fp8_f32(f[2], f[3], lo, true);
      int hi = __builtin_amdgcn_cvt_pk_fp8_f32(f[4], f[5], 0, false);
      hi = __builtin_amdgcn_cvt_pk_fp8_f32(f[6], f[7], hi, true);
      uint2v o; o[0] = (unsigned)lo; o[1] = (unsigned)hi;
      *(uint2v*)&z8[((size_t)(b * 1024 + hw0 + h)) * 256 + d0 + dq * 8] = o;
    }
  } else {
    const int k = (bid - 1024) * 4 + (t >> 6);
    const int lane = t & 63;
    floatx4 v = *(const floatx4*)&cb[((size_t)k << 8) + lane * 4];
    float a = v[0] * CSCALE, b2 = v[1] * CSCALE, c = v[2] * CSCALE, d2 = v[3] * CSCALE;
    int r = __builtin_amdgcn_cvt_pk_fp8_f32(a, b2, 0, false);
    r = __builtin_amdgcn_cvt_pk_fp8_f32(c, d2, r, true);
    *(unsigned int*)&c8[((size_t)k << 8) + lane * 4] = (unsigned)r;
    float s = a * a + b2 * b2 + c * c + d2 * d2;  // ||8192 c||^2
#pragma unroll
    for (int off = 32; off; off >>= 1) s += __shfl_down(s, off);
    if (lane == 0) norms[k] = s;
  }
}

// ---- main: MX-fp8 32x32x64, 4 cy-tiles per block (A/norms amortized) ----
// A whole-K in VGPR; B in padded 272B LDS rows (zero-conflict, immediate
// addressing); barrier-free K-loop; plain u64 stores (no atomics).
__global__ __launch_bounds__(256, 2) void gemm_argmin(
    const unsigned char* __restrict__ z8, const unsigned char* __restrict__ c8,
    const float* __restrict__ norms, u64* __restrict__ partial)
{
  // B panel: 256 rows x 272 B = 69632; best2 u64[512] at +69632
  __shared__ alignas(16) unsigned char lds8[69632 + 4096];

  const int tid = threadIdx.x;
  const int lane = tid & 63;
  const int wid = tid >> 6;
  const int wm = wid >> 1;  // code half (64 codes)
  const int wn = wid & 1;   // zrow half (128 zrows)

  // XCD chunked swizzle: nwg = 2048 (%8==0). XCD owns 4 cy-groups (16 panels).
  const int bid = blockIdx.x;
  const int swz = (bid & 7) * 256 + (bid >> 3);
  const int cx = swz & 63;   // 64 code panels
  const int cyg = swz >> 6;  // 32 zrow groups (4 panels each)
  const int m0 = cx * 128;

  const int l31 = lane & 31;
  const int hi = lane >> 5;
  const int k2 = hi << 1;

  // ---- A (codes): global -> VGPR, whole K=256, ONCE per block ----
  intx8 af[2][4];  // [ti][kt]
#pragma unroll
  for (int ti = 0; ti < 2; ++ti) {
    const unsigned char* arow =
        c8 + ((size_t)(m0 + wm * 64 + ti * 32 + l31) << 8) + k2 * 16;
#pragma unroll
    for (int kt = 0; kt < 4; ++kt) {
      intx4 lo = *(const intx4*)(arow + kt * 64);
      intx4 hv = *(const intx4*)(arow + kt * 64 + 16);
      intx8 o;
#pragma unroll
      for (int w = 0; w < 4; ++w) { o[w] = lo[w]; o[4 + w] = hv[w]; }
      af[ti][kt] = o;
    }
  }

  // ---- norms: once per block ----
  floatx4 nv[2][4];
#pragma unroll
  for (int ti = 0; ti < 2; ++ti)
#pragma unroll
    for (int rq = 0; rq < 4; ++rq)
      nv[ti][rq] = *(const floatx4*)&norms[m0 + wm * 64 + ti * 32 + rq * 8 + 4 * hi];

  u64* best2 = (u64*)(lds8 + 69632);  // [256 zrows][2 wm]
  const unsigned char* gB0 = z8 + ((size_t)(cyg * 1024) << 8);
  unsigned char* dstb = lds8 + (tid >> 4) * 272 + (tid & 15) * 16;
  const unsigned char* rb = lds8 + (size_t)(wn * 128 + l31) * 272 + k2 * 16;

#pragma unroll 1
  for (int t = 0; t < 4; ++t) {
    // ---- stage B tile t (reg-staged into padded rows; two 8-deep batches) ----
    // Safe vs previous tile's LDS reads: epilogue's internal __syncthreads
    // guarantees all waves are past K-loop(t-1) before any wave reaches here.
    {
      const unsigned char* gsrc = gB0 + ((size_t)(t * 256) << 8) + tid * 16;
      intx4 tmp[8];
#pragma unroll
      for (int c = 0; c < 8; ++c) tmp[c] = *(const intx4*)(gsrc + c * 4096);
#pragma unroll
      for (int c = 0; c < 8; ++c) *(intx4*)(dstb + c * 4352) = tmp[c];
#pragma unroll
      for (int c = 0; c < 8; ++c) tmp[c] = *(const intx4*)(gsrc + (8 + c) * 4096);
#pragma unroll
      for (int c = 0; c < 8; ++c) *(intx4*)(dstb + (8 + c) * 4352) = tmp[c];
    }
    __syncthreads();

    floatx16 acc[2][4];
#pragma unroll
    for (int i = 0; i < 2; ++i)
#pragma unroll
      for (int j = 0; j < 4; ++j)
#pragma unroll
        for (int e = 0; e < 16; ++e) acc[i][j][e] = 0.f;

    // ---- barrier-free K-loop: all-immediate ds_reads off one base ----
#pragma unroll
    for (int kt = 0; kt < 4; ++kt) {
      intx8 bf[4];
#pragma unroll
      for (int tj = 0; tj < 4; ++tj) {
        intx4 lo = *(const intx4*)(rb + tj * 8704 + kt * 64);
        intx4 hv = *(const intx4*)(rb + tj * 8704 + kt * 64 + 16);
        intx8 o;
#pragma unroll
        for (int w = 0; w < 4; ++w) { o[w] = lo[w]; o[4 + w] = hv[w]; }
        bf[tj] = o;
      }
#pragma unroll
      for (int ti = 0; ti < 2; ++ti)
#pragma unroll
        for (int tj = 0; tj < 4; ++tj)
          acc[ti][tj] = __builtin_amdgcn_mfma_scale_f32_32x32x64_f8f6f4(
              af[ti][kt], bf[tj], acc[ti][tj], 0, 0, 0, 127, 0, 127);
    }

    // ---- epilogue: fused argmin; ties -> smallest code; plain store ----
    // D layout: zrow = lane&31; code-in-tile = (reg&3) + 8*(reg>>2) + 4*hi
#pragma unroll
    for (int tj = 0; tj < 4; ++tj) {
      float best = __builtin_inff();
      int bc = 0;
#pragma unroll
      for (int ti = 0; ti < 2; ++ti)
#pragma unroll
        for (int rq = 0; rq < 4; ++rq)
#pragma unroll
          for (int rl = 0; rl < 4; ++rl) {
            float sc = fmaf(acc[ti][tj][rq * 4 + rl], -16384.f, nv[ti][rq][rl]);
            int cd = m0 + wm * 64 + ti * 32 + rq * 8 + 4 * hi + rl;
            if (sc < best) { best = sc; bc = cd; }
          }
      uint32_t u = __float_as_uint(best);
      u ^= ((uint32_t)((int32_t)u >> 31) | 0x80000000u);  // monotone-sortable
      u64 p = ((u64)u << 32) | (uint32_t)bc;
      {
        u64 o = (u64)__shfl_xor((long long)p, 32);
        p = o < p ? o : p;
      }
      if (lane < 32) best2[(size_t)(wn * 128 + tj * 32 + l31) * 2 + wm] = p;
    }
    __syncthreads();  // best2 ready; also orders next tile's B writes
    {
      u64 a = best2[tid * 2], b = best2[tid * 2 + 1];
      partial[(size_t)cx * NROWS + cyg * 1024 + t * 256 + tid] = a < b ? a : b;
    }
  }
}

// ---- reduce 64 code-panel partials -> final code (deterministic) ----
__global__ __launch_bounds__(256) void reduce_amin(const u64* __restrict__ partial,
                                                   uint32_t* __restrict__ codei)
{
  const int n = blockIdx.x * 256 + threadIdx.x;
  u64 m = partial[n];
#pragma unroll 8
  for (int x = 1; x < 64; ++x) {
    u64 v = partial[(size_t)x * NROWS + n];
    m = v < m ? v : m;
  }
  codei[n] = (uint32_t)m;
}

// ---- gather + output + per-block loss partials (8 elems/thread) ----
__global__ __launch_bounds__(256) void gather_out(
    const float* __restrict__ z, const float* __restrict__ cb,
    const uint32_t* __restrict__ codei,
    float* __restrict__ out, float* __restrict__ partial)
{
  const int t = threadIdx.x;
  const size_t e0 = ((size_t)blockIdx.x * 256 + t) * 8;
  const int d = (int)((e0 >> 10) & 255);
  const int b = (int)(e0 >> 18);
  const int n0 = b * 1024 + (int)(e0 & 1023);
  uint4v k0 = *(const uint4v*)&codei[n0];
  uint4v k1 = *(const uint4v*)&codei[n0 + 4];
  floatx4 z0 = *(const floatx4*)&z[e0];
  floatx4 z1 = *(const floatx4*)&z[e0 + 4];
  floatx4 q0, q1;
#pragma unroll
  for (int m = 0; m < 4; ++m) {
    q0[m] = cb[((size_t)k0[m] << 8) + d];
    q1[m] = cb[((size_t)k1[m] << 8) + d];
  }
  *(floatx4*)&out[e0] = q0;
  *(floatx4*)&out[e0 + 4] = q1;
  float s = 0.f;
#pragma unroll
  for (int m = 0; m < 4; ++m) {
    float d0 = z0[m] - q0[m], d1 = z1[m] - q1[m];
    s += d0 * d0 + d1 * d1;
  }
#pragma unroll
  for (int off = 32; off; off >>= 1) s += __shfl_down(s, off);
  __shared__ float ps[4];
  if ((t & 63) == 0) ps[t >> 6] = s;
  __syncthreads();
  if (t == 0) partial[blockIdx.x] = ps[0] + ps[1] + ps[2] + ps[3];
}

// ---- deterministic final reduction + scalar outputs ----
__global__ __launch_bounds__(256) void finalize(const float* __restrict__ partial,
                                                float* __restrict__ out)
{
  const int t = threadIdx.x;
  float s = 0.f;
#pragma unroll
  for (int i = 0; i < 16; ++i) s += partial[i * 256 + t];
#pragma unroll
  for (int off = 32; off; off >>= 1) s += __shfl_down(s, off);
  __shared__ float ps[4];
  if ((t & 63) == 0) ps[t >> 6] = s;
  __syncthreads();
  if (t == 0) {
    float m = (ps[0] + ps[1] + ps[2] + ps[3]) / (float)QELEMS;
    out[QELEMS] = m;             // codebook_loss
    out[QELEMS + 1] = 0.2f * m;  // commitment_loss
  }
}

extern "C" void kernel_launch(void* const* d_in, const int* in_sizes, int n_in,
                              void* d_out, int out_size, void* d_ws, size_t ws_size,
                              hipStream_t stream)
{
  const float* z = (const float*)d_in[0];
  const float* cb = (const float*)d_in[1];
  float* out = (float*)d_out;
  char* ws = (char*)d_ws;

  // ws layout (bytes)
  unsigned char* z8 = (unsigned char*)(ws + 0);       //  8,388,608
  unsigned char* c8 = (unsigned char*)(ws + 8388608); //  2,097,152
  float* norms = (float*)(ws + 10485760);             //    131,072 (padded)
  u64* pamin = (u64*)(ws + 10616832);                 // 16,777,216 (64 x 32768)
  uint32_t* codei = (uint32_t*)(ws + 27394048);       //    131,072
  float* lpart = (float*)(ws + 27525120);             //     16,384
  // total: 27,541,504 bytes

  prep_all<<<3072, 256, 0, stream>>>(z, cb, z8, c8, norms);
  gemm_argmin<<<2048, 256, 0, stream>>>(z8, c8, norms, pamin);
  reduce_amin<<<NROWS / 256, 256, 0, stream>>>(pamin, codei);
  gather_out<<<QELEMS / 2048, 256, 0, stream>>>(z, cb, codei, out, lpart);
  finalize<<<1, 256, 0, stream>>>(lpart, out);
}